// Round 11
// baseline (131.344 us; speedup 1.0000x reference)
//
#include <hip/hip_runtime.h>
#include <hip/hip_bf16.h>
#include <math.h>

constexpr int kB = 128;
constexpr int kT = 256;
constexpr int kC = 384;
constexpr int kH = 64;

using bf16x8 = __attribute__((ext_vector_type(8))) short;  // 8 bf16 = 4 VGPRs
using f32x4  = __attribute__((ext_vector_type(4))) float;

union BF4 { short4 s; __hip_bfloat162 h[2]; };

__device__ inline short4 cvt4(float4 a) {
    BF4 u;
    u.h[0] = __float22bfloat162_rn(float2{a.x, a.y});
    u.h[1] = __float22bfloat162_rn(float2{a.z, a.w});
    return u.s;
}
__device__ inline short bf1(float f) {
    __hip_bfloat16 h = __float2bfloat16(f);
    return *(short*)&h;
}

// ---------------------------------------------------------------------------
// Kernel 0: Wt[n][k] bf16, n in [0,192) = (w*64+h), k in [0,384).
// Wk rows pre-scaled by 384^-0.5 * log2(e) (exp2-domain softmax, R10 win).
// ---------------------------------------------------------------------------
__global__ void prep_kernel(const float* __restrict__ Wq,
                            const float* __restrict__ Wk,
                            const float* __restrict__ Wv,
                            __hip_bfloat16* __restrict__ Wt) {
    int idx = blockIdx.x * 256 + threadIdx.x;     // [0, 192*384)
    int n = idx / kC, c = idx % kC;
    int w = n >> 6, h = n & 63;
    const float* W = (w == 0) ? Wq : (w == 1) ? Wk : Wv;
    float val = W[c * kH + h];
    if (w == 1) val *= 0.07362222374744683f;      // 384^-0.5 * log2(e)
    Wt[idx] = __float2bfloat16(val);
}

// ---------------------------------------------------------------------------
// Fused kernel — R10 structure (best measured: dur 109.9) with BK 32 -> 64:
// phase 1 drops from 12 barrier-stepped K-iterations to 6. Rationale: with
// 1 block/CU every __syncthreads costs a full vmcnt(0)+lgkmcnt(0) drain that
// nothing can hide; halving the barrier count amortizes each drain over 2x
// the MFMA+staging work (48 MFMAs/step/wave). The 121.9 KB double-buffered
// staging doesn't fit beside the 89 KB homes, so staging ALIASES the homes
// (R7 proved this correctness pattern: staging dies at the final mstep
// barrier; homes are written only in the post-barrier epilogue).
// LDS arena (shorts): homes Qs@0(18432) Ks@18432(9216) VTs@27648(16896);
// staging As0@0(17408) As1@17408 Bs0@34816(13056) Bs1@47872 -> end 60928
// (121,856 B, 1 block/CU). Phase-2 P buffer moved to the staging tail
// (offset 44544+, dead in phase 2 — old As[0] slot now aliases live Qs!).
// A-frag LDS reads at row stride 68 shorts = 34 dwords: lane i (m16) hits
// dwords {2i..2i+3} mod 32 -> each bank touched by exactly 2 lanes = the
// measured-free 2-way class (m136). B-frag identical form.
// Phase 2: R10's batch softmax + exp2 + Pb round-trip, byte-identical.
// Ledger: more waves x, split x, destaged x, caps<256 fatal, 2-deep ~0.
// ---------------------------------------------------------------------------
__global__ __launch_bounds__(512, 2) void fused_kernel(
    const float* __restrict__ x, const __hip_bfloat16* __restrict__ Wt,
    float* __restrict__ out)
{
    __shared__ __align__(16) short SM[60928];      // 121,856 B arena
    short* Qs  = SM;              // [s][h]    stride 72, 256 rows (home)
    short* Ks  = SM + 18432;      // [t-t0][h] stride 72, 128 rows (home)
    short* VTs = SM + 27648;      // [h][s]    stride 264, 64 rows (home)
    // staging (phase 1 only; aliases homes, dead before epilogue):
    short* As0 = SM;              // x tile bf16 [m][kk], stride 68, 256 rows
    short* As1 = SM + 17408;
    short* Bs0 = SM + 34816;      // Wt tile [n][kk], stride 68, 192 rows
    short* Bs1 = SM + 47872;

    const int bid  = blockIdx.x;
    const int b    = ((bid >> 4) << 3) | (bid & 7);   // batch
    const int half = ((bid >> 3) & 1) ^ 1;            // heavy (1) first
    const int t0   = half * 128;

    const int tid  = threadIdx.x;
    const int wave = tid >> 6, lane = tid & 63;
    const int m16  = lane & 15, quad = lane >> 4;
    const int wm = wave & 1, wn = wave >> 1;       // m-half, 3-n-tile slice
    const short* wt = (const short*)Wt;
    const float* xb = x + (size_t)b * kT * kC;

    // wave-uniform activity masks for the light half (M = 128)
    const bool mfmaAct = (half == 1) || (wm == 0);

    // dead-K: heavy half's rows 0-127 K-projection is discarded -> skip
    bool kskip[3];
#pragma unroll
    for (int j = 0; j < 3; ++j) {
        const int nt = wn * 3 + j;
        kskip[j] = (half == 1) && (wm == 0) && (nt >= 4) && (nt < 8);
    }

    // ---------------- Phase 1: projection, BK=64, 6 steps ----------------
    // A staging: 2 threads/row (rows = tid>>1, wave-uniform light skip),
    // 32-col fp32 chunk (tid&1)*32. B staging: 3 bf16x8 chunks/thread over
    // 192 rows x 8 chunks (c = tid + 512p, n = c>>3, kk = (c&7)*8).
    const int arow = tid >> 1, acol = (tid & 1) * 32;
    const bool aAct = (half == 1) || (arow < 128);

    float4 la[8]; bf16x8 lb[3];
    auto glod = [&](int k0) {
        if (aAct) {
#pragma unroll
            for (int i = 0; i < 8; ++i)
                la[i] = *(const float4*)(xb + (size_t)arow * kC + k0 + acol + 4 * i);
        }
#pragma unroll
        for (int p = 0; p < 3; ++p) {
            int c = tid + 512 * p, n = c >> 3, kk = (c & 7) * 8;
            lb[p] = *(const bf16x8*)(wt + (size_t)n * kC + k0 + kk);
        }
    };
    auto swr = [&](int d) {
        short* Ad = d ? As1 : As0;
        short* Bd = d ? Bs1 : Bs0;
        if (aAct) {
#pragma unroll
            for (int i = 0; i < 8; ++i)
                *(short4*)&Ad[arow * 68 + acol + 4 * i] = cvt4(la[i]);
        }
#pragma unroll
        for (int p = 0; p < 3; ++p) {
            int c = tid + 512 * p, n = c >> 3, kk = (c & 7) * 8;
            *(bf16x8*)&Bd[n * 68 + kk] = lb[p];
        }
    };

    f32x4 acc[8][3];
#pragma unroll
    for (int mt = 0; mt < 8; ++mt)
#pragma unroll
        for (int j = 0; j < 3; ++j) acc[mt][j] = f32x4{0.f, 0.f, 0.f, 0.f};

    auto mstep = [&](int d) {
        if (!mfmaAct) return;
        const short* Ad = d ? As1 : As0;
        const short* Bd = d ? Bs1 : Bs0;
#pragma unroll
        for (int ks = 0; ks < 2; ++ks) {
            bf16x8 af[8];
#pragma unroll
            for (int mt = 0; mt < 8; ++mt)
                af[mt] = *(const bf16x8*)
                    &Ad[(wm * 128 + mt * 16 + m16) * 68 + ks * 32 + quad * 8];
#pragma unroll
            for (int j = 0; j < 3; ++j) {
                if (!kskip[j]) {
                    const bf16x8 bfr = *(const bf16x8*)
                        &Bd[((wn * 3 + j) * 16 + m16) * 68 + ks * 32 + quad * 8];
#pragma unroll
                    for (int mt = 0; mt < 8; ++mt)
                        acc[mt][j] = __builtin_amdgcn_mfma_f32_16x16x32_bf16(
                            af[mt], bfr, acc[mt][j], 0, 0, 0);
                }
            }
        }
    };

    glod(0);
    swr(0);
    __syncthreads();

    for (int s = 0; s < 6; ++s) {
        const int d = s & 1;
        if (s < 5) glod((s + 1) * 64);             // next tile in flight
        mstep(d);
        if (s < 5) swr(d ^ 1);
        __syncthreads();                            // final one also fences
    }                                               // staging-read vs home-write

    // epilogue: C-layout (col = m16 in-tile, rows = quad*4+r) -> LDS homes
    if (mfmaAct) {
#pragma unroll
        for (int mt = 0; mt < 8; ++mt) {
            const int mbase = wm * 128 + mt * 16 + quad * 4;
#pragma unroll
            for (int j = 0; j < 3; ++j) {
                const int nt = wn * 3 + j;             // n-tile 0..11
                const int w  = nt >> 2;                // 0=q, 1=k, 2=v
                const int h  = (nt & 3) * 16 + m16;
                if (w == 2) {
                    float4 f = make_float4(acc[mt][j][0], acc[mt][j][1],
                                           acc[mt][j][2], acc[mt][j][3]);
                    *(short4*)&VTs[h * 264 + mbase] = cvt4(f);   // s = mbase..+3
                } else if (w == 1) {
                    if ((mbase >> 7) == half) {        // rows [t0, t0+128)
#pragma unroll
                        for (int r = 0; r < 4; ++r)
                            Ks[(mbase + r - t0) * 72 + h] = bf1(acc[mt][j][r]);
                    }
                } else {
#pragma unroll
                    for (int r = 0; r < 4; ++r)
                        Qs[(mbase + r) * 72 + h] = bf1(acc[mt][j][r]);
                }
            }
        }
    }
    __syncthreads();   // phase boundary: Qs/Ks/VTs all visible

    // -------- Phase 2: attention, BATCH softmax (barrier-free) ----------
    const int wband = t0 + wave * 16;              // this wave's t-band
    // P buffer: staging tail BEYOND the homes (offset 44544..60928 is dead
    // in phase 2; the old As[0] slot now aliases the LIVE Qs home).
    short* Pb = SM + 44544 + wave * 1152;          // 16x72 bf16 per wave

    const bf16x8 ka0 = *(const bf16x8*)&Ks[(wave * 16 + m16) * 72 + quad * 8];
    const bf16x8 ka1 = *(const bf16x8*)&Ks[(wave * 16 + m16) * 72 + quad * 8 + 32];

    const int ilast = wband >> 6;                  // wave-uniform
    const int jmaxd = wave & 3;                    // diag-tile jmax

    // all S' tiles in registers: S[i][j][r], s = i*64+j*16+quad*4+r, t = m16
    f32x4 S[4][4];
    const f32x4 Z = f32x4{0.f, 0.f, 0.f, 0.f};
#pragma unroll
    for (int i = 0; i < 4; ++i)
#pragma unroll
        for (int j = 0; j < 4; ++j) S[i][j] = Z;

    __builtin_amdgcn_s_setprio(1);
#pragma unroll
    for (int i = 0; i < 4; ++i) {
        if (i <= ilast) {
#pragma unroll
            for (int j = 0; j < 4; ++j) {
                if (i < ilast || j <= jmaxd) {
                    const int s = i * 64 + j * 16 + m16;
                    bf16x8 qb0 = *(const bf16x8*)&Qs[s * 72 + quad * 8];
                    bf16x8 qb1 = *(const bf16x8*)&Qs[s * 72 + quad * 8 + 32];
                    S[i][j] = __builtin_amdgcn_mfma_f32_16x16x32_bf16(qb0, ka0, S[i][j], 0, 0, 0);
                    S[i][j] = __builtin_amdgcn_mfma_f32_16x16x32_bf16(qb1, ka1, S[i][j], 0, 0, 0);
                }
            }
        }
    }
    __builtin_amdgcn_s_setprio(0);

    // diagonal mask on tile (ilast, jmaxd): s > t -> -inf   (static indices)
#pragma unroll
    for (int i = 0; i < 4; ++i)
#pragma unroll
        for (int j = 0; j < 4; ++j)
            if (i == ilast && j == jmaxd) {
#pragma unroll
                for (int r = 0; r < 4; ++r)
                    if (quad * 4 + r > m16) S[i][j][r] = -INFINITY;
            }

    // ONE global max over the whole row (t = wband + m16); log2 domain
    float rm = -INFINITY;
#pragma unroll
    for (int i = 0; i < 4; ++i)
#pragma unroll
        for (int j = 0; j < 4; ++j)
            if (i <= ilast && (i < ilast || j <= jmaxd))
#pragma unroll
                for (int r = 0; r < 4; ++r) rm = fmaxf(rm, S[i][j][r]);
    rm = fmaxf(rm, __shfl_xor(rm, 16, 64));
    rm = fmaxf(rm, __shfl_xor(rm, 32, 64));

    // ONE exp2 pass in place + row sum (exp2f -> single v_exp_f32)
    float l_ = 0.f;
#pragma unroll
    for (int i = 0; i < 4; ++i)
#pragma unroll
        for (int j = 0; j < 4; ++j)
            if (i <= ilast && (i < ilast || j <= jmaxd))
#pragma unroll
                for (int r = 0; r < 4; ++r) {
                    const float e = exp2f(S[i][j][r] - rm);
                    S[i][j][r] = e;
                    l_ += e;
                }
    l_ += __shfl_xor(l_, 16, 64);
    l_ += __shfl_xor(l_, 32, 64);

    // PV: per i-tile, pack P -> Pb, read back as A-fragment, 8 MFMAs
    f32x4 O[4];
#pragma unroll
    for (int i = 0; i < 4; ++i) O[i] = f32x4{0.f, 0.f, 0.f, 0.f};

#pragma unroll
    for (int i = 0; i < 4; ++i) {
        if (i <= ilast) {
#pragma unroll
            for (int j = 0; j < 4; ++j)
#pragma unroll
                for (int p = 0; p < 2; ++p) {
                    __hip_bfloat162 w = __float22bfloat162_rn(
                        float2{S[i][j][2 * p], S[i][j][2 * p + 1]});
                    *(__hip_bfloat162*)&Pb[m16 * 72 + j * 16 + quad * 4 + 2 * p] = w;
                }
            bf16x8 pf0 = *(const bf16x8*)&Pb[m16 * 72 + quad * 8];
            bf16x8 pf1 = *(const bf16x8*)&Pb[m16 * 72 + quad * 8 + 32];

            __builtin_amdgcn_s_setprio(1);
#pragma unroll
            for (int ht = 0; ht < 4; ++ht) {
                bf16x8 vb0 = *(const bf16x8*)&VTs[(ht * 16 + m16) * 264 + i * 64 + quad * 8];
                bf16x8 vb1 = *(const bf16x8*)&VTs[(ht * 16 + m16) * 264 + i * 64 + quad * 8 + 32];
                O[ht] = __builtin_amdgcn_mfma_f32_16x16x32_bf16(pf0, vb0, O[ht], 0, 0, 0);
                O[ht] = __builtin_amdgcn_mfma_f32_16x16x32_bf16(pf1, vb1, O[ht], 0, 0, 0);
            }
            __builtin_amdgcn_s_setprio(0);
        }
    }

    // epilogue: 1/l broadcast from t=m16 holders, scale, store
    float lbc[4];
#pragma unroll
    for (int r = 0; r < 4; ++r)
        lbc[r] = __shfl(l_, (quad << 4) | (quad * 4 + r), 64);
#pragma unroll
    for (int r = 0; r < 4; ++r) {
        const float inv = 1.f / lbc[r];
        const size_t row = (size_t)(b * kT + wband + quad * 4 + r);
#pragma unroll
        for (int ht = 0; ht < 4; ++ht)
            out[row * kH + ht * 16 + m16] = O[ht][r] * inv;
    }
}

// ---------------------------------------------------------------------------
extern "C" void kernel_launch(void* const* d_in, const int* in_sizes, int n_in,
                              void* d_out, int out_size, void* d_ws, size_t ws_size,
                              hipStream_t stream) {
    const float* x  = (const float*)d_in[0];
    const float* Wq = (const float*)d_in[1];
    const float* Wk = (const float*)d_in[2];
    const float* Wv = (const float*)d_in[3];
    float* out = (float*)d_out;

    __hip_bfloat16* Wt = (__hip_bfloat16*)d_ws;    // 147 KB [n][k]

    prep_kernel<<<(192 * kC) / 256, 256, 0, stream>>>(Wq, Wk, Wv, Wt);
    fused_kernel<<<dim3(256), 512, 0, stream>>>(x, Wt, out);
}

// Round 12
// 110.628 us; speedup vs baseline: 1.1873x; 1.1873x over previous
//
#include <hip/hip_runtime.h>
#include <hip/hip_bf16.h>
#include <math.h>

constexpr int kB = 128;
constexpr int kT = 256;
constexpr int kC = 384;
constexpr int kH = 64;

using bf16x8 = __attribute__((ext_vector_type(8))) short;  // 8 bf16 = 4 VGPRs
using f32x4  = __attribute__((ext_vector_type(4))) float;

union BF4 { short4 s; __hip_bfloat162 h[2]; };

__device__ inline short4 cvt4(float4 a) {
    BF4 u;
    u.h[0] = __float22bfloat162_rn(float2{a.x, a.y});
    u.h[1] = __float22bfloat162_rn(float2{a.z, a.w});
    return u.s;
}
__device__ inline short bf1(float f) {
    __hip_bfloat16 h = __float2bfloat16(f);
    return *(short*)&h;
}

// ---------------------------------------------------------------------------
// Kernel 0: Wt[n][k] bf16, n in [0,192) = (w*64+h), k in [0,384).
// Wk rows pre-scaled by 384^-0.5 * log2(e) (exp2-domain softmax, R10 win).
// ---------------------------------------------------------------------------
__global__ void prep_kernel(const float* __restrict__ Wq,
                            const float* __restrict__ Wk,
                            const float* __restrict__ Wv,
                            __hip_bfloat16* __restrict__ Wt) {
    int idx = blockIdx.x * 256 + threadIdx.x;     // [0, 192*384)
    int n = idx / kC, c = idx % kC;
    int w = n >> 6, h = n & 63;
    const float* W = (w == 0) ? Wq : (w == 1) ? Wk : Wv;
    float val = W[c * kH + h];
    if (w == 1) val *= 0.07362222374744683f;      // 384^-0.5 * log2(e)
    Wt[idx] = __float2bfloat16(val);
}

// ---------------------------------------------------------------------------
// Fused kernel — R10 structure (best measured: dur 109.9) + two micro-cuts:
//  (a) the step-11 __syncthreads is removed (protects nothing: no swr after
//      it, epilogue writes are wave-private, phase boundary re-fences);
//  (b) PV loop issues all 8 V-fragment ds_reads BEFORE the P pack/round-trip
//      so they fly under the cvt_pk VALU work.
// Phase 1: M x 192 GEMM (M=256 heavy / 128 light), BK=32, 12 steps, LDS
// double-buffer, XCD pair swizzle, dead-K skip. Phase 2: batch softmax
// (S[4][4] in regs, one max, one exp2 pass, one sum), Pb round-trip, setprio.
// Ledger: more waves x (R2), split x (R3/4), destaged x (R8), caps<256
// fatal (R7), 2-deep ~0 (R5), BK=64 x (R11: per-step load latency, not
// barrier count, dominates phase 1).
// ---------------------------------------------------------------------------
__global__ __launch_bounds__(512, 2) void fused_kernel(
    const float* __restrict__ x, const __hip_bfloat16* __restrict__ Wt,
    float* __restrict__ out)
{
    __shared__ short Qs[256 * 72];      // [s][h]
    __shared__ short Ks[128 * 72];      // [t-t0][h]
    __shared__ short VTs[64 * 264];     // [h][s]
    __shared__ short As[2][256 * 36];   // x tile bf16 [m][kk], stride 36
    __shared__ short Bs[2][192 * 36];   // Wt tile    [n][kk], stride 36

    const int bid  = blockIdx.x;
    const int b    = ((bid >> 4) << 3) | (bid & 7);   // batch
    const int half = ((bid >> 3) & 1) ^ 1;            // heavy (1) first
    const int t0   = half * 128;

    const int tid  = threadIdx.x;
    const int wave = tid >> 6, lane = tid & 63;
    const int m16  = lane & 15, quad = lane >> 4;
    const int wm = wave & 1, wn = wave >> 1;       // m-half, 3-n-tile slice
    const short* wt = (const short*)Wt;
    const float* xb = x + (size_t)b * kT * kC;

    // wave-uniform activity masks for the light half (M = 128)
    const bool mfmaAct = (half == 1) || (wm == 0);

    // dead-K: heavy half's rows 0-127 K-projection is discarded -> skip
    bool kskip[3];
#pragma unroll
    for (int j = 0; j < 3; ++j) {
        const int nt = wn * 3 + j;
        kskip[j] = (half == 1) && (wm == 0) && (nt >= 4) && (nt < 8);
    }

    // ---------------- Phase 1: projection ----------------
    const int arow = tid >> 1, acol = (tid & 1) * 16;
    const bool aAct = (half == 1) || (arow < 128);

    float4 la[4]; bf16x8 lb0, lb1;
    auto glod = [&](int k0) {
        if (aAct) {
#pragma unroll
            for (int i = 0; i < 4; ++i)
                la[i] = *(const float4*)(xb + (size_t)arow * kC + k0 + acol + 4 * i);
        }
        {
            int n = tid >> 2, kk = (tid & 3) * 8;
            lb0 = *(const bf16x8*)(wt + (size_t)n * kC + k0 + kk);
        }
        if (tid < 256) {
            int c = tid + 512;
            int n = c >> 2, kk = (c & 3) * 8;
            lb1 = *(const bf16x8*)(wt + (size_t)n * kC + k0 + kk);
        }
    };
    auto swr = [&](int d) {
        if (aAct) {
#pragma unroll
            for (int i = 0; i < 4; ++i)
                *(short4*)&As[d][arow * 36 + acol + 4 * i] = cvt4(la[i]);
        }
        {
            int n = tid >> 2, kk = (tid & 3) * 8;
            *(bf16x8*)&Bs[d][n * 36 + kk] = lb0;
        }
        if (tid < 256) {
            int c = tid + 512;
            int n = c >> 2, kk = (c & 3) * 8;
            *(bf16x8*)&Bs[d][n * 36 + kk] = lb1;
        }
    };

    f32x4 acc[8][3];
#pragma unroll
    for (int mt = 0; mt < 8; ++mt)
#pragma unroll
        for (int j = 0; j < 3; ++j) acc[mt][j] = f32x4{0.f, 0.f, 0.f, 0.f};

    glod(0);
    swr(0);
    __syncthreads();

    for (int s = 0; s < 12; ++s) {
        const int d = s & 1;
        if (s < 11) glod((s + 1) * 32);            // next tile in flight

        if (mfmaAct) {
            bf16x8 af[8];
#pragma unroll
            for (int mt = 0; mt < 8; ++mt)
                af[mt] = *(const bf16x8*)&As[d][(wm * 128 + mt * 16 + m16) * 36 + quad * 8];
#pragma unroll
            for (int j = 0; j < 3; ++j) {
                if (!kskip[j]) {
                    const bf16x8 bfr =
                        *(const bf16x8*)&Bs[d][((wn * 3 + j) * 16 + m16) * 36 + quad * 8];
#pragma unroll
                    for (int mt = 0; mt < 8; ++mt)
                        acc[mt][j] = __builtin_amdgcn_mfma_f32_16x16x32_bf16(
                            af[mt], bfr, acc[mt][j], 0, 0, 0);
                }
            }
        }

        if (s < 11) {
            swr(d ^ 1);
            __syncthreads();       // step s=11 needs no barrier: no swr after,
        }                          // epilogue writes are wave-private, and the
    }                              // phase boundary below re-fences everything

    // epilogue: C-layout (col = m16 in-tile, rows = quad*4+r) -> LDS homes
    if (mfmaAct) {
#pragma unroll
        for (int mt = 0; mt < 8; ++mt) {
            const int mbase = wm * 128 + mt * 16 + quad * 4;
#pragma unroll
            for (int j = 0; j < 3; ++j) {
                const int nt = wn * 3 + j;             // n-tile 0..11
                const int w  = nt >> 2;                // 0=q, 1=k, 2=v
                const int h  = (nt & 3) * 16 + m16;
                if (w == 2) {
                    float4 f = make_float4(acc[mt][j][0], acc[mt][j][1],
                                           acc[mt][j][2], acc[mt][j][3]);
                    *(short4*)&VTs[h * 264 + mbase] = cvt4(f);   // s = mbase..+3
                } else if (w == 1) {
                    if ((mbase >> 7) == half) {        // rows [t0, t0+128)
#pragma unroll
                        for (int r = 0; r < 4; ++r)
                            Ks[(mbase + r - t0) * 72 + h] = bf1(acc[mt][j][r]);
                    }
                } else {
#pragma unroll
                    for (int r = 0; r < 4; ++r)
                        Qs[(mbase + r) * 72 + h] = bf1(acc[mt][j][r]);
                }
            }
        }
    }
    __syncthreads();   // phase boundary: Qs/Ks/VTs all visible

    // -------- Phase 2: attention, BATCH softmax (barrier-free) ----------
    const int wband = t0 + wave * 16;              // this wave's t-band
    short* Pb = &As[0][0] + wave * 1152;           // dead As: 16x72 bf16/wave

    const bf16x8 ka0 = *(const bf16x8*)&Ks[(wave * 16 + m16) * 72 + quad * 8];
    const bf16x8 ka1 = *(const bf16x8*)&Ks[(wave * 16 + m16) * 72 + quad * 8 + 32];

    const int ilast = wband >> 6;                  // wave-uniform
    const int jmaxd = wave & 3;                    // diag-tile jmax

    // all S' tiles in registers: S[i][j][r], s = i*64+j*16+quad*4+r, t = m16
    f32x4 S[4][4];
    const f32x4 Z = f32x4{0.f, 0.f, 0.f, 0.f};
#pragma unroll
    for (int i = 0; i < 4; ++i)
#pragma unroll
        for (int j = 0; j < 4; ++j) S[i][j] = Z;

    __builtin_amdgcn_s_setprio(1);
#pragma unroll
    for (int i = 0; i < 4; ++i) {
        if (i <= ilast) {
#pragma unroll
            for (int j = 0; j < 4; ++j) {
                if (i < ilast || j <= jmaxd) {
                    const int s = i * 64 + j * 16 + m16;
                    bf16x8 qb0 = *(const bf16x8*)&Qs[s * 72 + quad * 8];
                    bf16x8 qb1 = *(const bf16x8*)&Qs[s * 72 + quad * 8 + 32];
                    S[i][j] = __builtin_amdgcn_mfma_f32_16x16x32_bf16(qb0, ka0, S[i][j], 0, 0, 0);
                    S[i][j] = __builtin_amdgcn_mfma_f32_16x16x32_bf16(qb1, ka1, S[i][j], 0, 0, 0);
                }
            }
        }
    }
    __builtin_amdgcn_s_setprio(0);

    // diagonal mask on tile (ilast, jmaxd): s > t -> -inf   (static indices)
#pragma unroll
    for (int i = 0; i < 4; ++i)
#pragma unroll
        for (int j = 0; j < 4; ++j)
            if (i == ilast && j == jmaxd) {
#pragma unroll
                for (int r = 0; r < 4; ++r)
                    if (quad * 4 + r > m16) S[i][j][r] = -INFINITY;
            }

    // ONE global max over the whole row (t = wband + m16); log2 domain
    float rm = -INFINITY;
#pragma unroll
    for (int i = 0; i < 4; ++i)
#pragma unroll
        for (int j = 0; j < 4; ++j)
            if (i <= ilast && (i < ilast || j <= jmaxd))
#pragma unroll
                for (int r = 0; r < 4; ++r) rm = fmaxf(rm, S[i][j][r]);
    rm = fmaxf(rm, __shfl_xor(rm, 16, 64));
    rm = fmaxf(rm, __shfl_xor(rm, 32, 64));

    // ONE exp2 pass in place + row sum (exp2f -> single v_exp_f32)
    float l_ = 0.f;
#pragma unroll
    for (int i = 0; i < 4; ++i)
#pragma unroll
        for (int j = 0; j < 4; ++j)
            if (i <= ilast && (i < ilast || j <= jmaxd))
#pragma unroll
                for (int r = 0; r < 4; ++r) {
                    const float e = exp2f(S[i][j][r] - rm);
                    S[i][j][r] = e;
                    l_ += e;
                }
    l_ += __shfl_xor(l_, 16, 64);
    l_ += __shfl_xor(l_, 32, 64);

    // PV: per i-tile — V-fragment ds_reads issued FIRST (independent of the
    // softmax/pack), then P pack -> Pb -> A-fragment read, then 8 MFMAs.
    f32x4 O[4];
#pragma unroll
    for (int i = 0; i < 4; ++i) O[i] = f32x4{0.f, 0.f, 0.f, 0.f};

#pragma unroll
    for (int i = 0; i < 4; ++i) {
        if (i <= ilast) {
            bf16x8 vb[4][2];
#pragma unroll
            for (int ht = 0; ht < 4; ++ht) {
                vb[ht][0] = *(const bf16x8*)&VTs[(ht * 16 + m16) * 264 + i * 64 + quad * 8];
                vb[ht][1] = *(const bf16x8*)&VTs[(ht * 16 + m16) * 264 + i * 64 + quad * 8 + 32];
            }
#pragma unroll
            for (int j = 0; j < 4; ++j)
#pragma unroll
                for (int p = 0; p < 2; ++p) {
                    __hip_bfloat162 w = __float22bfloat162_rn(
                        float2{S[i][j][2 * p], S[i][j][2 * p + 1]});
                    *(__hip_bfloat162*)&Pb[m16 * 72 + j * 16 + quad * 4 + 2 * p] = w;
                }
            bf16x8 pf0 = *(const bf16x8*)&Pb[m16 * 72 + quad * 8];
            bf16x8 pf1 = *(const bf16x8*)&Pb[m16 * 72 + quad * 8 + 32];

            __builtin_amdgcn_s_setprio(1);
#pragma unroll
            for (int ht = 0; ht < 4; ++ht) {
                O[ht] = __builtin_amdgcn_mfma_f32_16x16x32_bf16(pf0, vb[ht][0], O[ht], 0, 0, 0);
                O[ht] = __builtin_amdgcn_mfma_f32_16x16x32_bf16(pf1, vb[ht][1], O[ht], 0, 0, 0);
            }
            __builtin_amdgcn_s_setprio(0);
        }
    }

    // epilogue: 1/l broadcast from t=m16 holders, scale, store
    float lbc[4];
#pragma unroll
    for (int r = 0; r < 4; ++r)
        lbc[r] = __shfl(l_, (quad << 4) | (quad * 4 + r), 64);
#pragma unroll
    for (int r = 0; r < 4; ++r) {
        const float inv = 1.f / lbc[r];
        const size_t row = (size_t)(b * kT + wband + quad * 4 + r);
#pragma unroll
        for (int ht = 0; ht < 4; ++ht)
            out[row * kH + ht * 16 + m16] = O[ht][r] * inv;
    }
}

// ---------------------------------------------------------------------------
extern "C" void kernel_launch(void* const* d_in, const int* in_sizes, int n_in,
                              void* d_out, int out_size, void* d_ws, size_t ws_size,
                              hipStream_t stream) {
    const float* x  = (const float*)d_in[0];
    const float* Wq = (const float*)d_in[1];
    const float* Wk = (const float*)d_in[2];
    const float* Wv = (const float*)d_in[3];
    float* out = (float*)d_out;

    __hip_bfloat16* Wt = (__hip_bfloat16*)d_ws;    // 147 KB [n][k]

    prep_kernel<<<(192 * kC) / 256, 256, 0, stream>>>(Wq, Wk, Wv, Wt);
    fused_kernel<<<dim3(256), 512, 0, stream>>>(x, Wt, out);
}